// Round 1
// 576.011 us; speedup vs baseline: 1.0321x; 1.0321x over previous
//
#include <hip/hip_runtime.h>
#include <hip/hip_bf16.h>

typedef unsigned short u16;
typedef __bf16 bf16x8 __attribute__((ext_vector_type(8)));
typedef float f32x4 __attribute__((ext_vector_type(4)));

#define N_NODES 200000
#define IN_FEAT 500
#define EMB 128
#define HID 64
#define NC 7
#define BM 128         // rows per block (4 waves x 2 row-tiles of 16)
#define KPAD 512       // 500 padded to 16 chunks of 32

// LDS strides (bf16 elements) — padded so fragment rows land on
// different banks (<=2-way aliasing, free on gfx950)
#define W1S 136        // Wt1       [64][136]
#define ES 136         // emb tile  [128][136]
#define HS 72          // h tile    [128][72]
#define W2S 72         // Wt2       [16][72]

// d_ws layout (u16 elements):
//   Wemb fragment-packed [c=16][t=8][lane=64][j=8]  (65536)
//   Wt1[n][k] (64x128) | Wt2[n][k] (16x64, n>=7 zero)
#define WS_WT1_OFF (128*512)
#define WS_WT2_OFF (128*512 + 64*128)
#define WS_TOTAL   (128*512 + 64*128 + 16*64)

__device__ __forceinline__ u16 cvt_bf16(float v) {
    __hip_bfloat16 h = __float2bfloat16(v);
    return *(u16*)&h;
}

__device__ __forceinline__ bf16x8 cvt8(float4 a, float4 b) {
    union { u16 u[8]; bf16x8 v; } pk;
    pk.u[0] = cvt_bf16(a.x); pk.u[1] = cvt_bf16(a.y);
    pk.u[2] = cvt_bf16(a.z); pk.u[3] = cvt_bf16(a.w);
    pk.u[4] = cvt_bf16(b.x); pk.u[5] = cvt_bf16(b.y);
    pk.u[6] = cvt_bf16(b.z); pk.u[7] = cvt_bf16(b.w);
    return pk.v;
}

__global__ __launch_bounds__(256) void prep_weights(
    const float* __restrict__ W_emb, const float* __restrict__ W_rt1,
    const float* __restrict__ W_rt2, u16* __restrict__ ws)
{
    int idx = blockIdx.x * 256 + threadIdx.x;
    float v;
    if (idx < 128*512) {
        // fragment-packed Wemb: idx = ((c*8 + t)*64 + lane)*8 + j
        // holds W_emb[k][n] with n = t*16 + (lane&15), k = c*32 + (lane>>4)*8 + j
        int j    = idx & 7;
        int lane = (idx >> 3) & 63;
        int t    = (idx >> 9) & 7;
        int c    = idx >> 12;
        int n = t*16 + (lane & 15);
        int k = c*32 + (lane >> 4)*8 + j;
        v = (k < IN_FEAT) ? W_emb[k*EMB + n] : 0.f;
    } else if (idx < WS_WT2_OFF) {             // Wt1[n][k]
        int j = idx - WS_WT1_OFF;
        int n = j >> 7, k = j & 127;
        v = W_rt1[k*HID + n];
    } else if (idx < WS_TOTAL) {               // Wt2[n][k], zero-pad n>=7
        int j = idx - WS_WT2_OFF;
        int n = j >> 6, k = j & 63;
        v = (n < NC) ? W_rt2[k*NC + n] : 0.f;
    } else {
        return;
    }
    ws[idx] = cvt_bf16(v);
}

__global__ __launch_bounds__(256) void mlp_fused(
    const float* __restrict__ F, const u16* __restrict__ Wf,
    const u16* __restrict__ Wt1g, const u16* __restrict__ Wt2g,
    const float* __restrict__ b_emb, const float* __restrict__ b1,
    const float* __restrict__ b2, float* __restrict__ out)
{
    __shared__ u16 W1l[HID * W1S];
    __shared__ u16 W2l[16 * W2S];
    __shared__ u16 Et[BM * ES];
    __shared__ u16 Ht[BM * HS];

    const int tid  = threadIdx.x;
    const int wave = tid >> 6;
    const int lane = tid & 63;
    const int l15  = lane & 15;
    const int q    = lane >> 4;            // quad 0..3
    const int row0 = blockIdx.x * BM;

    // ---- stage Wt1 (64x128) and Wt2 (16x64) into LDS once (bf16) ----
    #pragma unroll
    for (int i = 0; i < 4; ++i) {
        int g = tid * 4 + i;               // 1024 groups of 8 elems
        int r = g >> 4, cc = (g & 15) * 8;
        *(uint4*)&W1l[r*W1S + cc] = *(const uint4*)&Wt1g[r*128 + cc];
    }
    if (tid < 128) {
        int r = tid >> 3, cc = (tid & 7) * 8;
        *(uint4*)&W2l[r*W2S + cc] = *(const uint4*)&Wt2g[r*64 + cc];
    }

    // ---- layer 1: emb = relu(F @ W_emb + b_emb), K=512 (padded) ----
    // A fragments straight from global (fp32 -> bf16 in reg), no LDS, no syncs.
    // B fragments streamed from fragment-packed L2-resident Wf.
    int ra = row0 + wave*32 + l15;         // row-tile 0
    int rb = ra + 16;                      // row-tile 1
    if (ra >= N_NODES) ra = N_NODES - 1;   // clamp (duplicate read, store guarded)
    if (rb >= N_NODES) rb = N_NODES - 1;
    const float* p0 = F + (size_t)ra * IN_FEAT + q*8;
    const float* p1 = F + (size_t)rb * IN_FEAT + q*8;
    const u16*   wl = Wf + lane*8;         // + c*4096 + t*512 (u16 units)

    f32x4 acc[2][8];
    #pragma unroll
    for (int m = 0; m < 2; ++m)
        #pragma unroll
        for (int t = 0; t < 8; ++t) acc[m][t] = (f32x4){0.f,0.f,0.f,0.f};

    // prefetch chunk 0 (k=0..31 all valid)
    float4 a0l = *(const float4*)(p0);
    float4 a0h = *(const float4*)(p0 + 4);
    float4 a1l = *(const float4*)(p1);
    float4 a1h = *(const float4*)(p1 + 4);

    for (int c = 0; c < 16; ++c) {
        bf16x8 fa0 = cvt8(a0l, a0h);
        bf16x8 fa1 = cvt8(a1l, a1h);

        if (c < 15) {
            const float* s0 = p0 + (c + 1) * 32;
            const float* s1 = p1 + (c + 1) * 32;
            if (c == 14) {
                // chunk 15 covers k=480..511; valid k<500.
                // q=0,1: all 8 valid; q=2: first 4 valid; q=3: none.
                float4 z = make_float4(0.f, 0.f, 0.f, 0.f);
                a0l = z; a0h = z; a1l = z; a1h = z;
                if (q < 3) { a0l = *(const float4*)s0; a1l = *(const float4*)s1; }
                if (q < 2) { a0h = *(const float4*)(s0 + 4);
                             a1h = *(const float4*)(s1 + 4); }
            } else {
                a0l = *(const float4*)s0; a0h = *(const float4*)(s0 + 4);
                a1l = *(const float4*)s1; a1h = *(const float4*)(s1 + 4);
            }
        }

        const u16* wc = wl + c * 4096;     // contiguous 8KB fragment stream
        #pragma unroll
        for (int t = 0; t < 8; ++t) {
            bf16x8 b = *(const bf16x8*)(wc + t * 512);
            acc[0][t] = __builtin_amdgcn_mfma_f32_16x16x32_bf16(fa0, b, acc[0][t], 0, 0, 0);
            acc[1][t] = __builtin_amdgcn_mfma_f32_16x16x32_bf16(fa1, b, acc[1][t], 0, 0, 0);
        }
    }

    // epilogue 1: bias + relu -> bf16 emb tile in LDS (transpose for layer 2)
    #pragma unroll
    for (int t = 0; t < 8; ++t) {
        float bias = b_emb[t*16 + l15];
        #pragma unroll
        for (int m = 0; m < 2; ++m) {
            #pragma unroll
            for (int r = 0; r < 4; ++r) {
                float v = acc[m][t][r] + bias;
                v = v > 0.f ? v : 0.f;
                Et[(wave*32 + m*16 + q*4 + r)*ES + t*16 + l15] = cvt_bf16(v);
            }
        }
    }
    __syncthreads();

    // ---- layer 2: h = relu(emb @ W_rt1 + b1), K=128 ----
    f32x4 acc2[2][4];
    #pragma unroll
    for (int m = 0; m < 2; ++m)
        #pragma unroll
        for (int t = 0; t < 4; ++t) acc2[m][t] = (f32x4){0.f,0.f,0.f,0.f};

    #pragma unroll
    for (int kc = 0; kc < 4; ++kc) {
        bf16x8 a0 = *(const bf16x8*)&Et[(wave*32 +      l15)*ES + kc*32 + q*8];
        bf16x8 a1 = *(const bf16x8*)&Et[(wave*32 + 16 + l15)*ES + kc*32 + q*8];
        #pragma unroll
        for (int t = 0; t < 4; ++t) {
            bf16x8 b = *(const bf16x8*)&W1l[(t*16 + l15)*W1S + kc*32 + q*8];
            acc2[0][t] = __builtin_amdgcn_mfma_f32_16x16x32_bf16(a0, b, acc2[0][t], 0, 0, 0);
            acc2[1][t] = __builtin_amdgcn_mfma_f32_16x16x32_bf16(a1, b, acc2[1][t], 0, 0, 0);
        }
    }
    #pragma unroll
    for (int t = 0; t < 4; ++t) {
        float bias = b1[t*16 + l15];
        #pragma unroll
        for (int m = 0; m < 2; ++m) {
            #pragma unroll
            for (int r = 0; r < 4; ++r) {
                float v = acc2[m][t][r] + bias;
                v = v > 0.f ? v : 0.f;
                Ht[(wave*32 + m*16 + q*4 + r)*HS + t*16 + l15] = cvt_bf16(v);
            }
        }
    }
    __syncthreads();

    // ---- layer 3: out = h @ W_rt2 + b2, K=64, N=7 (padded to 16) ----
    f32x4 acc3[2];
    acc3[0] = (f32x4){0.f,0.f,0.f,0.f};
    acc3[1] = (f32x4){0.f,0.f,0.f,0.f};
    #pragma unroll
    for (int kc = 0; kc < 2; ++kc) {
        bf16x8 b  = *(const bf16x8*)&W2l[l15*W2S + kc*32 + q*8];
        bf16x8 a0 = *(const bf16x8*)&Ht[(wave*32 +      l15)*HS + kc*32 + q*8];
        bf16x8 a1 = *(const bf16x8*)&Ht[(wave*32 + 16 + l15)*HS + kc*32 + q*8];
        acc3[0] = __builtin_amdgcn_mfma_f32_16x16x32_bf16(a0, b, acc3[0], 0, 0, 0);
        acc3[1] = __builtin_amdgcn_mfma_f32_16x16x32_bf16(a1, b, acc3[1], 0, 0, 0);
    }
    if (l15 < NC) {
        float bias = b2[l15];
        #pragma unroll
        for (int m = 0; m < 2; ++m) {
            #pragma unroll
            for (int r = 0; r < 4; ++r) {
                int row = row0 + wave*32 + m*16 + q*4 + r;
                if (row < N_NODES)
                    out[(size_t)row * NC + l15] = acc3[m][r] + bias;
            }
        }
    }
}

extern "C" void kernel_launch(void* const* d_in, const int* in_sizes, int n_in,
                              void* d_out, int out_size, void* d_ws, size_t ws_size,
                              hipStream_t stream) {
    // inputs: 0=adj(unused) 1=features 2=W_emb 3=b_emb 4=W_rt1 5=b_rt1 6=W_rt2 7=b_rt2
    const float* F     = (const float*)d_in[1];
    const float* W_emb = (const float*)d_in[2];
    const float* b_emb = (const float*)d_in[3];
    const float* W_rt1 = (const float*)d_in[4];
    const float* b_rt1 = (const float*)d_in[5];
    const float* W_rt2 = (const float*)d_in[6];
    const float* b_rt2 = (const float*)d_in[7];
    u16* ws    = (u16*)d_ws;
    float* out = (float*)d_out;

    int prep_blocks = (WS_TOTAL + 255) / 256;
    prep_weights<<<prep_blocks, 256, 0, stream>>>(W_emb, W_rt1, W_rt2, ws);

    int grid = (N_NODES + BM - 1) / BM;    // 1563
    mlp_fused<<<grid, 256, 0, stream>>>(
        F, ws, ws + WS_WT1_OFF, ws + WS_WT2_OFF,
        b_emb, b_rt1, b_rt2, out);
}